// Round 6
// baseline (344.375 us; speedup 1.0000x reference)
//
#include <hip/hip_runtime.h>
#include <hip/hip_bf16.h>
#include <math.h>

#define NN 50000
#define EE 800000
#define FIN 128
#define FOUT 32
#define HEADS 8
#define NT 16
#define HF 256          // HEADS*FOUT
#define TH (NT*HEADS)   // 128
#define CMAX 128        // max per-node degree held in LDS (Poisson(16) max ~45)

typedef __attribute__((ext_vector_type(8))) short bf16x8;
typedef __attribute__((ext_vector_type(4))) float f32x4;

static __device__ __forceinline__ unsigned short f2b(float f) {
    __hip_bfloat16 h = __float2bfloat16(f);
    return *reinterpret_cast<unsigned short*>(&h);
}

// ---- Prep: x -> bf16 (row-major), fc_w -> bf16 transposed [col][k] ----
#define XQ (NN * FIN / 4)   // 1,600,000 float4 chunks
__global__ __launch_bounds__(256) void k_prep(
    const float* __restrict__ x, const float* __restrict__ fc_w,
    unsigned short* __restrict__ xh, unsigned short* __restrict__ fwT)
{
    int i = blockIdx.x * 256 + threadIdx.x;
    if (i < XQ) {
        float4 v = ((const float4*)x)[i];
        uint2 o;
        o.x = (unsigned)f2b(v.x) | ((unsigned)f2b(v.y) << 16);
        o.y = (unsigned)f2b(v.z) | ((unsigned)f2b(v.w) << 16);
        ((uint2*)xh)[i] = o;
    } else {
        int j = i - XQ;                     // fwT: 32768 elems, j = col*128 + k
        if (j < HF * FIN) {
            int col = j >> 7, k = j & 127;
            fwT[j] = f2b(fc_w[k * HF + col]);
        }
    }
}

// ---- MFMA projection: nf = x @ fc_w (bf16 in, f32 acc) + a1 + nt epilogues ----
// 4 waves/block; wave computes 16 nodes x 256 cols. No cross-wave sync needed.
__global__ __launch_bounds__(256) void k_gemm(
    const unsigned short* __restrict__ xh, const unsigned short* __restrict__ fwT,
    const float* __restrict__ attn_l, const float* __restrict__ attn_r,
    unsigned short* __restrict__ nfh, float* __restrict__ a1,
    float* __restrict__ nt)
{
    __shared__ float ps[4][16][260];        // 66.6 KB, per-wave slabs
    const int w    = threadIdx.x >> 6;
    const int lane = threadIdx.x & 63;
    const int node0 = blockIdx.x * 64 + w * 16;
    const int mrow = lane & 15;
    const int kg   = lane >> 4;

    // A fragments: 4 K-chunks of 32; lane holds A[mrow][kc*32 + kg*8 + j]
    bf16x8 afr[4];
    const int arow = node0 + mrow;
    if (arow < NN) {
#pragma unroll
        for (int kc = 0; kc < 4; kc++)
            afr[kc] = *(const bf16x8*)&xh[(size_t)arow * FIN + kc * 32 + kg * 8];
    } else {
#pragma unroll
        for (int kc = 0; kc < 4; kc++) afr[kc] = (bf16x8)0;
    }

#pragma unroll
    for (int ct = 0; ct < 16; ct++) {
        f32x4 acc = {0.f, 0.f, 0.f, 0.f};
#pragma unroll
        for (int kc = 0; kc < 4; kc++) {
            bf16x8 bfr = *(const bf16x8*)&fwT[(ct * 16 + mrow) * FIN + kc * 32 + kg * 8];
            acc = __builtin_amdgcn_mfma_f32_16x16x32_bf16(afr[kc], bfr, acc, 0, 0, 0);
        }
#pragma unroll
        for (int r = 0; r < 4; r++)
            ps[w][kg * 4 + r][ct * 16 + mrow] = acc[r];
    }

    // ---- nf write: bf16, coalesced; lane covers cols lane*4..+3 ----
    for (int i = 0; i < 16; i++) {
        int n = node0 + i;
        if (n >= NN) break;
        float4 v = *(const float4*)&ps[w][i][lane * 4];
        uint2 o;
        o.x = (unsigned)f2b(v.x) | ((unsigned)f2b(v.y) << 16);
        o.y = (unsigned)f2b(v.z) | ((unsigned)f2b(v.w) << 16);
        *(uint2*)&nfh[(size_t)n * HF + lane * 4] = o;
    }

    // ---- a1: 16 nodes x 8 heads = 128 tasks ----
    for (int it = 0; it < 2; it++) {
        int task = it * 64 + lane;
        int ni = task >> 3, h = task & 7;
        int n = node0 + ni;
        float s = 0.f;
#pragma unroll
        for (int f = 0; f < FOUT; f++)
            s += ps[w][ni][f * HEADS + h] * attn_l[f * HEADS + h];
        if (n < NN) a1[n * HEADS + h] = s;
    }

    // ---- nt: 16 nodes x 128 (tt,h) = 2048 tasks ----
    for (int it = 0; it < 32; it++) {
        int task = it * 64 + lane;
        int ni = task >> 7, rem = task & 127;
        int tt = rem >> 3, h = rem & 7;
        int n = node0 + ni;
        const float* ar = attn_r + tt * (FOUT * HEADS);
        float s = 0.f;
#pragma unroll
        for (int f = 0; f < FOUT; f++)
            s += ps[w][ni][f * HEADS + h] * ar[f * HEADS + h];
        if (n < NN) nt[n * TH + rem] = s;
    }
}

// ---- CSR build: histogram of dst ----
__global__ __launch_bounds__(256) void k_hist(
    const int* __restrict__ dst, int* __restrict__ deg)
{
    int e = blockIdx.x * 256 + threadIdx.x;
    if (e >= EE) return;
    atomicAdd(&deg[dst[e]], 1);
}

// ---- CSR build: single-block exclusive scan deg -> rowptr[NN+1] ----
#define SCAN_T 1024
__global__ __launch_bounds__(1024) void k_scan(
    const int* __restrict__ deg, int* __restrict__ rowptr)
{
    __shared__ int part[SCAN_T];
    const int t = threadIdx.x;
    const int CH = (NN + SCAN_T - 1) / SCAN_T;  // 49
    int begin = t * CH;
    int end = begin + CH; if (end > NN) end = NN;
    if (begin > NN) begin = NN;
    int s = 0;
    for (int i = begin; i < end; i++) s += deg[i];
    part[t] = s;
    __syncthreads();
    for (int off = 1; off < SCAN_T; off <<= 1) {
        int v = (t >= off) ? part[t - off] : 0;
        __syncthreads();
        part[t] += v;
        __syncthreads();
    }
    int excl = (t == 0) ? 0 : part[t - 1];
    for (int i = begin; i < end; i++) {
        rowptr[i] = excl;
        excl += deg[i];
    }
    if (t == SCAN_T - 1) rowptr[NN] = EE;
}

// ---- CSR build: scatter records {e, src*TH+etype*HEADS}; deg doubles as cursor ----
__global__ __launch_bounds__(256) void k_scatter(
    const int* __restrict__ dst, const int* __restrict__ src,
    const int* __restrict__ et, const int* __restrict__ rowptr,
    int* __restrict__ deg, int2* __restrict__ recs)
{
    int e = blockIdx.x * 256 + threadIdx.x;
    if (e >= EE) return;
    int d = dst[e];
    int pos = atomicAdd(&deg[d], -1) - 1;      // unique slot deg-1..0
    int2 rec;
    rec.x = e;
    rec.y = src[e] * TH + et[e] * HEADS;
    recs[rowptr[d] + pos] = rec;
}

// ---- Fused per-node kernel: logits+exp, softmax denom in regs,
//      gather-aggregate, attn write, bias/mean/ELU epilogue ----
__global__ __launch_bounds__(256) void k_agg(
    const unsigned short* __restrict__ nfh, const float* __restrict__ a1,
    const float* __restrict__ nt, const int2* __restrict__ recs,
    const int* __restrict__ rowptr, const float* __restrict__ bias,
    float* __restrict__ A, float* __restrict__ ret)
{
    __shared__ float exs[4][CMAX * HEADS];  // 16 KB
    __shared__ int   sbuf[4][CMAX];         // 2 KB
    __shared__ int   ebuf[4][CMAX];         // 2 KB
    const int w    = threadIdx.x >> 6;
    const int lane = threadIdx.x & 63;
    const int n = blockIdx.x * 4 + w;
    if (n >= NN) return;
    const int start = rowptr[n];
    const int cnt   = rowptr[n + 1] - start;
    const int h  = lane & 7;
    const int ei = lane >> 3;
    const int half = lane & 1;

    const float a1h = a1[n * HEADS + h];
    float denl = 0.f;
    float4 acc = make_float4(0.f, 0.f, 0.f, 0.f);

    for (int base = 0; base < cnt; base += CMAX) {
        const int c = (cnt - base < CMAX) ? (cnt - base) : CMAX;
        for (int p0 = 0; p0 < c; p0 += 8) {
            int p = p0 + ei;
            if (p < c) {
                int2 rec = recs[start + base + p];
                float a = a1h + nt[rec.y + h];
                a = (a > 0.f) ? a : 0.2f * a;
                float ex = expf(a);
                exs[w][p * HEADS + h] = ex;
                denl += ex;
                if (h == 0) { sbuf[w][p] = rec.y >> 7; ebuf[w][p] = rec.x; }
            }
        }
        asm volatile("s_waitcnt lgkmcnt(0)" ::: "memory");
        for (int p = 0; p < c; p++) {
            int s = sbuf[w][p];
            float4 ex4 = *(const float4*)(&exs[w][p * HEADS + half * 4]);
            uint2 u = *(const uint2*)(nfh + (size_t)s * HF + lane * 4);
            float vx = __uint_as_float(u.x << 16);
            float vy = __uint_as_float(u.x & 0xFFFF0000u);
            float vz = __uint_as_float(u.y << 16);
            float vw = __uint_as_float(u.y & 0xFFFF0000u);
            acc.x += vx * ex4.x; acc.y += vy * ex4.y;
            acc.z += vz * ex4.z; acc.w += vw * ex4.w;
        }
        asm volatile("s_waitcnt lgkmcnt(0)" ::: "memory");
    }

    float den = denl;
    den += __shfl_xor(den, 8, 64);
    den += __shfl_xor(den, 16, 64);
    den += __shfl_xor(den, 32, 64);
    const float inv = (den > 0.f) ? 1.f / den : 0.f;

    if (cnt <= CMAX) {
        for (int p0 = 0; p0 < cnt; p0 += 8) {
            int p = p0 + ei;
            if (p < cnt) A[ebuf[w][p] * HEADS + h] = exs[w][p * HEADS + h] * inv;
        }
    } else {
        for (int p0 = 0; p0 < cnt; p0 += 8) {
            int p = p0 + ei;
            if (p < cnt) {
                int2 rec = recs[start + p];
                float a = a1h + nt[rec.y + h];
                a = (a > 0.f) ? a : 0.2f * a;
                A[rec.x * HEADS + h] = expf(a) * inv;
            }
        }
    }

    float4 invc;
    invc.x = __shfl(inv, half * 4 + 0, 64);
    invc.y = __shfl(inv, half * 4 + 1, 64);
    invc.z = __shfl(inv, half * 4 + 2, 64);
    invc.w = __shfl(inv, half * 4 + 3, 64);
    float4 b = *(const float4*)(&bias[lane * 4]);
    acc.x = acc.x * invc.x + b.x;
    acc.y = acc.y * invc.y + b.y;
    acc.z = acc.z * invc.z + b.z;
    acc.w = acc.w * invc.w + b.w;

    for (int m = 8; m <= 32; m <<= 1) {
        acc.x += __shfl_xor(acc.x, m, 64);
        acc.y += __shfl_xor(acc.y, m, 64);
        acc.z += __shfl_xor(acc.z, m, 64);
        acc.w += __shfl_xor(acc.w, m, 64);
    }
    if (lane < 8) {
        float4 o;
        o.x = acc.x * 0.125f; o.y = acc.y * 0.125f;
        o.z = acc.z * 0.125f; o.w = acc.w * 0.125f;
        o.x = (o.x > 0.f) ? o.x : (expf(o.x) - 1.f);
        o.y = (o.y > 0.f) ? o.y : (expf(o.y) - 1.f);
        o.z = (o.z > 0.f) ? o.z : (expf(o.z) - 1.f);
        o.w = (o.w > 0.f) ? o.w : (expf(o.w) - 1.f);
        *(float4*)(&ret[n * FOUT + lane * 4]) = o;
    }
}

extern "C" void kernel_launch(void* const* d_in, const int* in_sizes, int n_in,
                              void* d_out, int out_size, void* d_ws, size_t ws_size,
                              hipStream_t stream)
{
    const float* x      = (const float*)d_in[0];
    const float* fc_w   = (const float*)d_in[1];
    const float* attn_l = (const float*)d_in[2];
    const float* attn_r = (const float*)d_in[3];
    const float* bias   = (const float*)d_in[4];
    const int*   src    = (const int*)d_in[5];
    const int*   dst    = (const int*)d_in[6];
    const int*   etype  = (const int*)d_in[7];

    float* out_attn = (float*)d_out;                 // [E, 1, HEADS]
    float* out_ret  = out_attn + (size_t)EE * HEADS; // [N, FOUT]

    // workspace layout (bytes)
    char* ws = (char*)d_ws;
    unsigned short* nfh = (unsigned short*)(ws);     // 25.6 MB
    float* a1     = (float*)(ws + 25600000);         // 1.6 MB
    float* nt     = (float*)(ws + 27200000);         // 25.6 MB
    int*   deg    = (int*)(ws + 52800000);           // 200 KB (also scatter cursor)
    int*   rowptr = (int*)(ws + 53000000);           // 200 KB + 4
    int2*  recs   = (int2*)(ws + 53200008);          // 6.4 MB
    unsigned short* xh  = (unsigned short*)(ws + 59600128);  // 12.8 MB
    unsigned short* fwT = (unsigned short*)(ws + 72400128);  // 64 KB

    hipMemsetAsync(deg, 0, (size_t)NN * 4, stream);

    k_prep<<<(XQ + HF * FIN + 255) / 256, 256, 0, stream>>>(x, fc_w, xh, fwT);

    k_gemm<<<(NN + 63) / 64, 256, 0, stream>>>(xh, fwT, attn_l, attn_r,
                                               nfh, a1, nt);

    k_hist<<<(EE + 255) / 256, 256, 0, stream>>>(dst, deg);
    k_scan<<<1, SCAN_T, 0, stream>>>(deg, rowptr);
    k_scatter<<<(EE + 255) / 256, 256, 0, stream>>>(dst, src, etype, rowptr, deg, recs);

    k_agg<<<(NN + 3) / 4, 256, 0, stream>>>(nfh, a1, nt, recs, rowptr, bias,
                                            out_attn, out_ret);
}